// Round 17
// baseline (78.107 us; speedup 1.0000x reference)
//
#include <hip/hip_runtime.h>
#include <math.h>

#define NB   16      // batch
#define NM   4096    // preds per image
#define NT   512     // targets per image
#define CAP  16      // max candidates per row (overflow -> exact fallback)
#define IOU_THR 0.1f
#define EPSG 1e-7f
#define NROWS (NB*NM)
#define T_BLK 1024           // threads per block (producer AND auction width)
#define NWIN  (NM / T_BLK)   // 4 ascending windows, 1 row/thread/window
#define PB_ROWS 256          // rows produced per block
#define SENT  0xFFFFFFFFu

// ---------------------------------------------------------------------------
// Fused kernel: 256 co-resident blocks (<=2/CU -> guaranteed simultaneous
// residency; spin-wait is deadlock-free by construction).
// Phase 1 (all blocks): produce candidates for rows [blk*256, blk*256+256)
//   (R13 v2 wave loop: 2 rows/pass, shared t_lds read, ballot compaction,
//   ascending-j, e-major storage) then device-scope signal prod_done[img].
// Phase 2 (blocks with blk%16==0): R10-protocol windowed auction for image
//   blk/16 (T_WIN=1024, 4 windows, barriers-only cross-wave visibility),
//   after acquire-spin until the image's 16 producer blocks signaled.
// Fused final reduce via device atomicAdd (fixed-order sum, deterministic).
// ---------------------------------------------------------------------------
__global__ __launch_bounds__(T_BLK) void fused_kernel(
    const float4* __restrict__ pred, const float4* __restrict__ tgt,
    int* __restrict__ counts, float2* __restrict__ cands,
    int* __restrict__ prod_done, float* __restrict__ per_img,
    int* __restrict__ done_ctr, float* __restrict__ out)
{
    __shared__ float4   t_lds[NT];       // 8 KB (shared by both phases)
    __shared__ unsigned claim[NT];       // 2 KB
    __shared__ int lastprop;
    __shared__ unsigned char winovf[NWIN];
    __shared__ int ovf_min, ovf_res;
    __shared__ float rvv[T_BLK / 64];  __shared__ int rjj[T_BLK / 64];
    __shared__ float rls[T_BLK / 64];  __shared__ float rcs[T_BLK / 64];

    const int blk = blockIdx.x, t = threadIdx.x;
    const int b   = blk >> 4;            // image of this block's rows
    const int wv  = t >> 6, lane = t & 63;

    // ---- stage targets of image b (reused by the auction phase) ----
    if (t < NT) t_lds[t] = tgt[b * NT + t];
    __syncthreads();

    // ================= Phase 1: produce 256 rows =================
    {
        const int row0 = blk * PB_ROWS + wv * 16;
        const unsigned long long lmask = (1ull << lane) - 1ull;
        float4 pa = pred[row0], pb = pred[row0 + 1];
        for (int rr = 0; rr < 16; rr += 2) {
            float4 p0 = pa, p1 = pb;
            if (rr + 2 < 16) { pa = pred[row0 + rr + 2]; pb = pred[row0 + rr + 3]; }
            float ap0 = (p0.z - p0.x) * (p0.w - p0.y);
            float ap1 = (p1.z - p1.x) * (p1.w - p1.y);
            int base0 = 0, base1 = 0;
            #pragma unroll
            for (int pass = 0; pass < NT / 64; ++pass) {
                int j = (pass << 6) + lane;
                float4 tb = t_lds[j];
                float at = (tb.z - tb.x) * (tb.w - tb.y);
                float w0 = fmaxf(fminf(p0.z, tb.z) - fmaxf(p0.x, tb.x), 0.f);
                float h0 = fmaxf(fminf(p0.w, tb.w) - fmaxf(p0.y, tb.y), 0.f);
                float in0 = w0 * h0;
                float iou0 = in0 / ((ap0 + at) - in0);   // ref association
                float w1 = fmaxf(fminf(p1.z, tb.z) - fmaxf(p1.x, tb.x), 0.f);
                float h1 = fmaxf(fminf(p1.w, tb.w) - fmaxf(p1.y, tb.y), 0.f);
                float in1 = w1 * h1;
                float iou1 = in1 / ((ap1 + at) - in1);
                bool q0 = iou0 > IOU_THR, q1 = iou1 > IOU_THR;
                unsigned long long m0 = __ballot(q0), m1 = __ballot(q1);
                if (q0) {
                    int off = base0 + __popcll(m0 & lmask);
                    if (off < CAP)
                        cands[(size_t)off * NROWS + row0 + rr]     = make_float2(iou0, __int_as_float(j));
                }
                if (q1) {
                    int off = base1 + __popcll(m1 & lmask);
                    if (off < CAP)
                        cands[(size_t)off * NROWS + row0 + rr + 1] = make_float2(iou1, __int_as_float(j));
                }
                base0 += __popcll(m0);
                base1 += __popcll(m1);
            }
            if (lane == 0) {
                counts[row0 + rr]     = base0;           // > CAP flags overflow
                counts[row0 + rr + 1] = base1;
            }
        }
    }
    __syncthreads();                     // all waves' stores issued
    if (t == 0) {
        __threadfence();                 // release counts/cands (device scope)
        atomicAdd(&prod_done[b], 1);
    }

    // ================= Phase 2: auction (1 block per image) =================
    if ((blk & 15) != 0) return;         // block-uniform: no barrier divergence

    if (t < NT) claim[t] = SENT;
    if (t < NWIN) winovf[t] = 0;
    if (t == 0) {
        lastprop = -1;
        while (__hip_atomic_load(&prod_done[b], __ATOMIC_ACQUIRE,
                                 __HIP_MEMORY_SCOPE_AGENT) < 16) {}
        __threadfence();                 // acquire producers' stores
    }
    __syncthreads();                     // claim/winovf init + acquire visible

    const int gbase = b * NM;
    int allCnt[NWIN];
    #pragma unroll
    for (int k = 0; k < NWIN; ++k) {
        allCnt[k] = counts[gbase + k * T_BLK + t];
        if (allCnt[k] > CAP) winovf[k] = 1;
    }
    float2 nC[CAP];
    #pragma unroll
    for (int e = 0; e < CAP; ++e) nC[e] = cands[(size_t)e * NROWS + gbase + t];
    __syncthreads();                      // winovf visible to all

    int rglob = 0;
    float2 cC[CAP];
    for (int w = 0; w < NWIN; ++w) {
        #pragma unroll
        for (int e = 0; e < CAP; ++e) cC[e] = nC[e];
        const int cCnt = allCnt[w];
        if (w + 1 < NWIN) {               // prefetch next window; hides under rounds
            #pragma unroll
            for (int e = 0; e < CAP; ++e)
                nC[e] = cands[(size_t)e * NROWS + gbase + (w + 1) * T_BLK + t];
        }
        const unsigned row = (unsigned)(w * T_BLK + t);
        int  stt  = (cCnt > 0 && cCnt <= CAP) ? 0 : 2;   // 0=UNRES 1=HOLD 2=DONE
        int  myj  = -1;
        bool isovf = (cCnt > CAP);
        int  ovfj  = -1;

        for (;;) {
            // ---- auction rounds to window fixed point (1 barrier/round) ----
            for (;;) {
                if (stt == 1 && claim[myj] != row) stt = 0;      // sniped: rejoin
                bool did = false;
                if (stt == 0) {
                    for (int it = 0; it <= CAP; ++it) {          // bounded retry
                        float bv = -1.f; int bj = -1;
                        #pragma unroll
                        for (int e = 0; e < CAP; ++e) {          // independent reads
                            float2 ce = cC[e];
                            int j = __float_as_int(ce.y) & (NT - 1);
                            unsigned cj = claim[j];
                            if (e < cCnt && cj >= row && ce.x > bv) { bv = ce.x; bj = j; }
                        }
                        if (bj < 0) { stt = 2; break; }          // invalid (permanent)
                        did = true;
                        unsigned old = atomicMin(&claim[bj], row);
                        if (old >= row) { myj = bj; stt = 1; break; }   // settled
                        // lost: claim[bj] < row is permanent -> excluded next scan
                    }
                }
                if (did) lastprop = rglob;    // benign: all writers store same value
                __syncthreads();
                int lp = lastprop;
                ++rglob;
                if (lp < rglob - 1) break;    // zero-proposal round: fixed point
            }
            // ---- overflow fallback (count > CAP, ~never) ----
            if (!winovf[w]) break;
            if (t == 0) ovf_min = 0x7FFFFFFF;
            __syncthreads();
            bool pend = isovf && (ovfj < 0 || claim[ovfj] != row);
            if (pend) atomicMin(&ovf_min, (int)row);
            __syncthreads();
            const int rowF = ovf_min;                            // uniform
            if (rowF == 0x7FFFFFFF) break;                       // window done
            {   // exact claim-aware argmax over all 512 targets (thread t = target t)
                float4 p4 = pred[gbase + rowF];                  // uniform address
                float v = -1.f; int bj = NT;
                if (t < NT) {
                    float4 tt = t_lds[t];
                    float area_p = (p4.z - p4.x) * (p4.w - p4.y);
                    float area_t = (tt.z - tt.x) * (tt.w - tt.y);
                    float wd = fmaxf(fminf(p4.z, tt.z) - fmaxf(p4.x, tt.x), 0.f);
                    float hd = fmaxf(fminf(p4.w, tt.w) - fmaxf(p4.y, tt.y), 0.f);
                    float inter = wd * hd;
                    float iou = inter / ((area_p + area_t) - inter);
                    bool freej = claim[t] > (unsigned)rowF;      // smaller = final-used
                    v = freej ? iou : -1.f;
                    bj = freej ? t : NT;
                }
                #pragma unroll
                for (int off = 1; off < 64; off <<= 1) {
                    float ov = __shfl_xor(v, off);
                    int   oj = __shfl_xor(bj, off);
                    if (ov > v || (ov == v && oj < bj)) { v = ov; bj = oj; }
                }
                if (lane == 0) { rvv[wv] = v; rjj[wv] = bj; }
            }
            __syncthreads();
            if (t == 0) {
                float v = rvv[0]; int bj = rjj[0];
                for (int q = 1; q < T_BLK / 64; ++q)
                    if (rvv[q] > v || (rvv[q] == v && rjj[q] < bj)) { v = rvv[q]; bj = rjj[q]; }
                if (v > IOU_THR) { ovf_res = bj; claim[bj] = (unsigned)rowF; }  // steal
                else ovf_res = -1;
            }
            __syncthreads();
            if ((int)row == rowF) {
                if (ovf_res >= 0) ovfj = ovf_res;   // matched (recorded in claim)
                else isovf = false;                 // permanently invalid
            }
            // displaced holder (if any) re-detected at next round's recheck
        }
    }
    __syncthreads();

    // ---- commit by target: claim[j]==r <=> r matched j (unique fixed point) ----
    float ls = 0.f, cs = 0.f;
    if (t < NT) {
        unsigned r = claim[t];
        if (r != SENT) {
            float4 p4 = pred[gbase + (int)r];
            float4 tt = t_lds[t];
            float inter = fmaxf(fminf(p4.z, tt.z) - fmaxf(p4.x, tt.x), 0.f) *
                          fmaxf(fminf(p4.w, tt.w) - fmaxf(p4.y, tt.y), 0.f);
            float area_p = (p4.z - p4.x) * (p4.w - p4.y);
            float area_t = (tt.z - tt.x) * (tt.w - tt.y);
            float uni = area_p + area_t - inter;
            float iou = inter / (uni + EPSG);
            float enc = (fmaxf(p4.z, tt.z) - fminf(p4.x, tt.x)) *
                        (fmaxf(p4.w, tt.w) - fminf(p4.y, tt.y));
            float giou = iou - (enc - uni) / (enc + EPSG);
            ls = 1.f - giou;
            cs = 1.f;
        }
    }
    #pragma unroll
    for (int off = 32; off >= 1; off >>= 1) {
        ls += __shfl_xor(ls, off);
        cs += __shfl_xor(cs, off);
    }
    if (lane == 0) { rls[wv] = ls; rcs[wv] = cs; }
    __syncthreads();
    if (t == 0) {
        float L = 0.f, C = 0.f;
        for (int q = 0; q < T_BLK / 64; ++q) { L += rls[q]; C += rcs[q]; }
        per_img[b] = (C > 0.f) ? L / C : 0.f;
        __threadfence();                                  // publish per_img[b]
        int ret = atomicAdd(done_ctr, 1);                 // device-scope
        if (ret == NB - 1) {                              // last image reduces
            __threadfence();                              // acquire all per_img
            volatile float* vp = per_img;
            float s = 0.f;
            for (int i = 0; i < NB; ++i) s += vp[i];      // fixed order
            out[0] = s / (float)NB;
        }
    }
}

extern "C" void kernel_launch(void* const* d_in, const int* in_sizes, int n_in,
                              void* d_out, int out_size, void* d_ws, size_t ws_size,
                              hipStream_t stream)
{
    const float4* pred = (const float4*)d_in[0];   // [16,4096,4] f32
    const float4* tgt  = (const float4*)d_in[1];   // [16,512,4]  f32

    char* ws = (char*)d_ws;
    // layout: counts [NROWS] i32 | cands [CAP*NROWS] float2 | per_img [NB] f32
    //         | sync block: done_ctr (1) + prod_done[NB]  (zeroed each launch)
    int*    counts  = (int*)ws;
    size_t  off1    = (size_t)NROWS * sizeof(int);                 // 256 KB
    float2* cands   = (float2*)(ws + off1);
    size_t  off2    = off1 + (size_t)CAP * NROWS * sizeof(float2); // +8 MB
    float*  per_img = (float*)(ws + off2);
    size_t  off3    = off2 + 64;                                   // aligned sync block
    int*    done_ctr  = (int*)(ws + off3);
    int*    prod_done = done_ctr + 1;

    hipMemsetAsync(done_ctr, 0, (NB + 1) * sizeof(int), stream);   // capture-legal
    fused_kernel<<<NROWS / PB_ROWS, T_BLK, 0, stream>>>(
        pred, tgt, counts, cands, prod_done, per_img, done_ctr, (float*)d_out);
}

// Round 18
// 72.135 us; speedup vs baseline: 1.0828x; 1.0828x over previous
//
#include <hip/hip_runtime.h>
#include <math.h>

#define NB   16      // batch
#define NM   4096    // preds per image
#define NT   512     // targets per image
#define CAP  16      // max candidates per row (overflow -> exact fallback)
#define IOU_THR 0.1f
#define EPSG 1e-7f
#define NROWS (NB*NM)
#define T_WIN 512            // threads per auction block (R10 measured-best)
#define NWIN  (NM / T_WIN)   // 8 ascending windows, 1 row/thread/window
#define SENT  0xFFFFFFFFu

// ---------------------------------------------------------------------------
// Kernel 1: wave-per-row candidate build, v3 (R15): 4 rows per pass (1/4 LDS
// reads, 4 independent VALU chains), pred loads software-pipelined. Ballot
// compaction, ascending-j order, transposed (e-major) storage. Zeroes the
// fused-reduce counter (block 0) each launch for graph-replay safety.
// ---------------------------------------------------------------------------
__global__ __launch_bounds__(256) void cand_kernel(
    const float4* __restrict__ pred, const float4* __restrict__ tgt,
    int* __restrict__ counts, float2* __restrict__ cands, int* __restrict__ done_ctr)
{
    __shared__ float4 t_lds[NT];
    const int rb = blockIdx.x * 64;          // 64 rows per block, same image
    const int b  = rb >> 12;                 // NM = 4096
    if (blockIdx.x == 0 && threadIdx.x == 0) *done_ctr = 0;
    for (int i = threadIdx.x; i < NT; i += 256)
        t_lds[i] = tgt[b * NT + i];
    __syncthreads();

    const int wv = threadIdx.x >> 6, lane = threadIdx.x & 63;
    const int row0 = rb + wv * 16;
    const unsigned long long lmask = (1ull << lane) - 1ull;

    float4 pn0 = pred[row0],     pn1 = pred[row0 + 1];
    float4 pn2 = pred[row0 + 2], pn3 = pred[row0 + 3];
    for (int rr = 0; rr < 16; rr += 4) {
        float4 p0 = pn0, p1 = pn1, p2 = pn2, p3 = pn3;
        if (rr + 4 < 16) {                   // prefetch next quad early
            pn0 = pred[row0 + rr + 4]; pn1 = pred[row0 + rr + 5];
            pn2 = pred[row0 + rr + 6]; pn3 = pred[row0 + rr + 7];
        }
        float ap0 = (p0.z - p0.x) * (p0.w - p0.y);
        float ap1 = (p1.z - p1.x) * (p1.w - p1.y);
        float ap2 = (p2.z - p2.x) * (p2.w - p2.y);
        float ap3 = (p3.z - p3.x) * (p3.w - p3.y);
        int base0 = 0, base1 = 0, base2 = 0, base3 = 0;
        #pragma unroll
        for (int pass = 0; pass < NT / 64; ++pass) {
            int j = (pass << 6) + lane;
            float4 t = t_lds[j];                   // shared by all 4 rows
            float at = (t.z - t.x) * (t.w - t.y);  // shared
            float w0 = fmaxf(fminf(p0.z, t.z) - fmaxf(p0.x, t.x), 0.f);
            float h0 = fmaxf(fminf(p0.w, t.w) - fmaxf(p0.y, t.y), 0.f);
            float in0 = w0 * h0;
            float iou0 = in0 / ((ap0 + at) - in0); // ref association
            float w1 = fmaxf(fminf(p1.z, t.z) - fmaxf(p1.x, t.x), 0.f);
            float h1 = fmaxf(fminf(p1.w, t.w) - fmaxf(p1.y, t.y), 0.f);
            float in1 = w1 * h1;
            float iou1 = in1 / ((ap1 + at) - in1);
            float w2 = fmaxf(fminf(p2.z, t.z) - fmaxf(p2.x, t.x), 0.f);
            float h2 = fmaxf(fminf(p2.w, t.w) - fmaxf(p2.y, t.y), 0.f);
            float in2 = w2 * h2;
            float iou2 = in2 / ((ap2 + at) - in2);
            float w3 = fmaxf(fminf(p3.z, t.z) - fmaxf(p3.x, t.x), 0.f);
            float h3 = fmaxf(fminf(p3.w, t.w) - fmaxf(p3.y, t.y), 0.f);
            float in3 = w3 * h3;
            float iou3 = in3 / ((ap3 + at) - in3);
            bool q0 = iou0 > IOU_THR, q1 = iou1 > IOU_THR;
            bool q2 = iou2 > IOU_THR, q3 = iou3 > IOU_THR;
            unsigned long long m0 = __ballot(q0), m1 = __ballot(q1);
            unsigned long long m2 = __ballot(q2), m3 = __ballot(q3);
            if (q0) {
                int off = base0 + __popcll(m0 & lmask);
                if (off < CAP)
                    cands[(size_t)off * NROWS + row0 + rr]     = make_float2(iou0, __int_as_float(j));
            }
            if (q1) {
                int off = base1 + __popcll(m1 & lmask);
                if (off < CAP)
                    cands[(size_t)off * NROWS + row0 + rr + 1] = make_float2(iou1, __int_as_float(j));
            }
            if (q2) {
                int off = base2 + __popcll(m2 & lmask);
                if (off < CAP)
                    cands[(size_t)off * NROWS + row0 + rr + 2] = make_float2(iou2, __int_as_float(j));
            }
            if (q3) {
                int off = base3 + __popcll(m3 & lmask);
                if (off < CAP)
                    cands[(size_t)off * NROWS + row0 + rr + 3] = make_float2(iou3, __int_as_float(j));
            }
            base0 += __popcll(m0); base1 += __popcll(m1);
            base2 += __popcll(m2); base3 += __popcll(m3);
        }
        if (lane == 0) {
            counts[row0 + rr]     = base0;         // > CAP flags overflow
            counts[row0 + rr + 1] = base1;
            counts[row0 + rr + 2] = base2;
            counts[row0 + rr + 3] = base3;
        }
    }
}

// ---------------------------------------------------------------------------
// Kernel 2: windowed auction — R10 protocol VERBATIM at T_WIN=512 (measured
// 39.6us), 8 ascending windows, 1 row/thread/window; fused final reduce
// (last block sums per_img in fixed index order -> deterministic).
// claim[j] = min proposer (monotone) -> unique fixed point == serial greedy.
// Cross-wave visibility via barriers only (R11 lesson).
// ---------------------------------------------------------------------------
__global__ __launch_bounds__(T_WIN) void win_auction(
    const float4* __restrict__ pred, const float4* __restrict__ tgt,
    const int* __restrict__ counts, const float2* __restrict__ cands,
    float* __restrict__ per_img, int* __restrict__ done_ctr,
    float* __restrict__ out)
{
    __shared__ float4   t_lds[NT];       // 8 KB
    __shared__ unsigned claim[NT];       // 2 KB
    __shared__ int lastprop;             // monotone round stamp
    __shared__ unsigned char winovf[NWIN];
    __shared__ int ovf_min, ovf_res;
    __shared__ float rvv[T_WIN / 64];  __shared__ int rjj[T_WIN / 64];
    __shared__ float rls[T_WIN / 64];  __shared__ float rcs[T_WIN / 64];

    const int b = blockIdx.x, t = threadIdx.x, gbase = b * NM;
    const int wv = t >> 6, lane = t & 63;

    t_lds[t] = tgt[b * NT + t];          // T_WIN == NT
    claim[t] = SENT;
    if (t < NWIN) winovf[t] = 0;
    if (t == 0) lastprop = -1;
    __syncthreads();

    // all counts up front (8 coalesced loads), flag overflow windows
    int allCnt[NWIN];
    #pragma unroll
    for (int k = 0; k < NWIN; ++k) {
        allCnt[k] = counts[gbase + k * T_WIN + t];
        if (allCnt[k] > CAP) winovf[k] = 1;
    }
    // prefetch window 0 candidates into registers
    float2 nC[CAP];
    #pragma unroll
    for (int e = 0; e < CAP; ++e) nC[e] = cands[(size_t)e * NROWS + gbase + t];
    __syncthreads();                      // winovf visible to all

    int rglob = 0;
    float2 cC[CAP];
    for (int w = 0; w < NWIN; ++w) {
        #pragma unroll
        for (int e = 0; e < CAP; ++e) cC[e] = nC[e];
        const int cCnt = allCnt[w];
        if (w + 1 < NWIN) {               // prefetch next window; hides under rounds
            #pragma unroll
            for (int e = 0; e < CAP; ++e)
                nC[e] = cands[(size_t)e * NROWS + gbase + (w + 1) * T_WIN + t];
        }
        const unsigned row = (unsigned)(w * T_WIN + t);
        int  stt  = (cCnt > 0 && cCnt <= CAP) ? 0 : 2;   // 0=UNRES 1=HOLD 2=DONE
        int  myj  = -1;
        bool isovf = (cCnt > CAP);
        int  ovfj  = -1;

        for (;;) {
            // ---- auction rounds to window fixed point (1 barrier/round) ----
            for (;;) {
                if (stt == 1 && claim[myj] != row) stt = 0;      // sniped: rejoin
                bool did = false;
                if (stt == 0) {
                    for (int it = 0; it <= CAP; ++it) {          // bounded retry
                        float bv = -1.f; int bj = -1;
                        #pragma unroll
                        for (int e = 0; e < CAP; ++e) {          // independent reads
                            float2 ce = cC[e];
                            int j = __float_as_int(ce.y) & (NT - 1);
                            unsigned cj = claim[j];
                            if (e < cCnt && cj >= row && ce.x > bv) { bv = ce.x; bj = j; }
                        }
                        if (bj < 0) { stt = 2; break; }          // invalid (permanent)
                        did = true;
                        unsigned old = atomicMin(&claim[bj], row);
                        if (old >= row) { myj = bj; stt = 1; break; }   // settled
                        // lost: claim[bj] < row is permanent -> excluded next scan
                    }
                }
                if (did) lastprop = rglob;    // benign: all writers store same value
                __syncthreads();
                int lp = lastprop;
                ++rglob;
                if (lp < rglob - 1) break;    // zero-proposal round: fixed point
            }
            // ---- overflow fallback (count > CAP, ~never) ----
            if (!winovf[w]) break;
            if (t == 0) ovf_min = 0x7FFFFFFF;
            __syncthreads();
            bool pend = isovf && (ovfj < 0 || claim[ovfj] != row);
            if (pend) atomicMin(&ovf_min, (int)row);
            __syncthreads();
            const int rowF = ovf_min;                            // uniform
            if (rowF == 0x7FFFFFFF) break;                       // window done
            {   // exact claim-aware argmax over all 512 targets (thread t = target t)
                float4 p4 = pred[gbase + rowF];                  // uniform address
                float4 tt = t_lds[t];
                float area_p = (p4.z - p4.x) * (p4.w - p4.y);
                float area_t = (tt.z - tt.x) * (tt.w - tt.y);
                float wd = fmaxf(fminf(p4.z, tt.z) - fmaxf(p4.x, tt.x), 0.f);
                float hd = fmaxf(fminf(p4.w, tt.w) - fmaxf(p4.y, tt.y), 0.f);
                float inter = wd * hd;
                float iou = inter / ((area_p + area_t) - inter);
                bool freej = claim[t] > (unsigned)rowF;          // smaller = final-used
                float v = freej ? iou : -1.f;
                int bj = freej ? t : NT;
                #pragma unroll
                for (int off = 1; off < 64; off <<= 1) {
                    float ov = __shfl_xor(v, off);
                    int   oj = __shfl_xor(bj, off);
                    if (ov > v || (ov == v && oj < bj)) { v = ov; bj = oj; }
                }
                if (lane == 0) { rvv[wv] = v; rjj[wv] = bj; }
            }
            __syncthreads();
            if (t == 0) {
                float v = rvv[0]; int bj = rjj[0];
                for (int q = 1; q < T_WIN / 64; ++q)
                    if (rvv[q] > v || (rvv[q] == v && rjj[q] < bj)) { v = rvv[q]; bj = rjj[q]; }
                if (v > IOU_THR) { ovf_res = bj; claim[bj] = (unsigned)rowF; }  // steal
                else ovf_res = -1;
            }
            __syncthreads();
            if ((int)row == rowF) {
                if (ovf_res >= 0) ovfj = ovf_res;   // matched (recorded in claim)
                else isovf = false;                 // permanently invalid
            }
            // displaced holder (if any) re-detected at next round's recheck
        }
    }
    __syncthreads();

    // ---- commit by target: claim[j]==r <=> r matched j (unique fixed point) ----
    float ls = 0.f, cs = 0.f;
    {
        unsigned r = claim[t];
        if (r != SENT) {
            float4 p4 = pred[gbase + (int)r];
            float4 tt = t_lds[t];
            float inter = fmaxf(fminf(p4.z, tt.z) - fmaxf(p4.x, tt.x), 0.f) *
                          fmaxf(fminf(p4.w, tt.w) - fmaxf(p4.y, tt.y), 0.f);
            float area_p = (p4.z - p4.x) * (p4.w - p4.y);
            float area_t = (tt.z - tt.x) * (tt.w - tt.y);
            float uni = area_p + area_t - inter;
            float iou = inter / (uni + EPSG);
            float enc = (fmaxf(p4.z, tt.z) - fminf(p4.x, tt.x)) *
                        (fmaxf(p4.w, tt.w) - fminf(p4.y, tt.y));
            float giou = iou - (enc - uni) / (enc + EPSG);
            ls = 1.f - giou;
            cs = 1.f;
        }
    }
    #pragma unroll
    for (int off = 32; off >= 1; off >>= 1) {
        ls += __shfl_xor(ls, off);
        cs += __shfl_xor(cs, off);
    }
    if (lane == 0) { rls[wv] = ls; rcs[wv] = cs; }
    __syncthreads();
    if (t == 0) {
        float L = 0.f, C = 0.f;
        for (int q = 0; q < T_WIN / 64; ++q) { L += rls[q]; C += rcs[q]; }
        per_img[b] = (C > 0.f) ? L / C : 0.f;
        __threadfence();                                  // publish per_img[b]
        int ret = atomicAdd(done_ctr, 1);                 // device-scope
        if (ret == NB - 1) {                              // last block reduces
            __threadfence();                              // acquire all per_img
            volatile float* vp = per_img;
            float s = 0.f;
            for (int i = 0; i < NB; ++i) s += vp[i];      // fixed order
            out[0] = s / (float)NB;
        }
    }
}

extern "C" void kernel_launch(void* const* d_in, const int* in_sizes, int n_in,
                              void* d_out, int out_size, void* d_ws, size_t ws_size,
                              hipStream_t stream)
{
    const float4* pred = (const float4*)d_in[0];   // [16,4096,4] f32
    const float4* tgt  = (const float4*)d_in[1];   // [16,512,4]  f32

    char* ws = (char*)d_ws;
    // layout: counts [NROWS] i32 | cands [CAP*NROWS] float2 | per_img [NB] f32 | ctr
    int*    counts  = (int*)ws;
    size_t  off1    = (size_t)NROWS * sizeof(int);                 // 256 KB
    float2* cands   = (float2*)(ws + off1);
    size_t  off2    = off1 + (size_t)CAP * NROWS * sizeof(float2); // +8 MB
    float*  per_img = (float*)(ws + off2);
    int*    done_ctr = (int*)(ws + off2 + 64);

    cand_kernel<<<NROWS / 64, 256, 0, stream>>>(pred, tgt, counts, cands, done_ctr);
    win_auction<<<NB, T_WIN, 0, stream>>>(pred, tgt, counts, cands, per_img,
                                          done_ctr, (float*)d_out);
}

// Round 19
// 56.316 us; speedup vs baseline: 1.3869x; 1.2809x over previous
//
#include <hip/hip_runtime.h>
#include <math.h>

#define NB   16      // batch
#define NM   4096    // preds per image
#define NT   512     // targets per image
#define CAP  16      // max candidates per row (overflow -> exact fallback)
#define IOU_THR 0.1f
#define EPSG 1e-7f
#define NROWS (NB*NM)
#define T_WIN 1024           // threads per auction block (measured-best: ~30us)
#define NWIN  (NM / T_WIN)   // 4 ascending windows, 1 row/thread/window
#define SENT  0xFFFFFFFFu

// ---------------------------------------------------------------------------
// Kernel 1: wave-per-row candidate build, v4: 4 rows per pass + fast-rcp IoU
// (v_rcp+v_mul replaces the ~10-op IEEE div; value only drives threshold and
// within-row ordering — exact GIoU is recomputed at commit) + 32 rows/block
// (2048 blocks, more TLP). Ballot compaction, ascending-j order, e-major
// storage. Zeroes the fused-reduce counter each launch (graph-replay safe).
// ---------------------------------------------------------------------------
__global__ __launch_bounds__(256) void cand_kernel(
    const float4* __restrict__ pred, const float4* __restrict__ tgt,
    int* __restrict__ counts, float2* __restrict__ cands, int* __restrict__ done_ctr)
{
    __shared__ float4 t_lds[NT];
    const int rb = blockIdx.x * 32;          // 32 rows per block, same image
    const int b  = rb >> 12;                 // NM = 4096
    if (blockIdx.x == 0 && threadIdx.x == 0) *done_ctr = 0;
    #pragma unroll
    for (int i = 0; i < 2; ++i)
        t_lds[i * 256 + threadIdx.x] = tgt[b * NT + i * 256 + threadIdx.x];
    __syncthreads();

    const int wv = threadIdx.x >> 6, lane = threadIdx.x & 63;
    const int row0 = rb + wv * 8;            // 8 rows per wave (2 quads)
    const unsigned long long lmask = (1ull << lane) - 1ull;

    float4 pn0 = pred[row0],     pn1 = pred[row0 + 1];
    float4 pn2 = pred[row0 + 2], pn3 = pred[row0 + 3];
    for (int rr = 0; rr < 8; rr += 4) {
        float4 p0 = pn0, p1 = pn1, p2 = pn2, p3 = pn3;
        if (rr + 4 < 8) {                    // prefetch next quad early
            pn0 = pred[row0 + rr + 4]; pn1 = pred[row0 + rr + 5];
            pn2 = pred[row0 + rr + 6]; pn3 = pred[row0 + rr + 7];
        }
        float ap0 = (p0.z - p0.x) * (p0.w - p0.y);
        float ap1 = (p1.z - p1.x) * (p1.w - p1.y);
        float ap2 = (p2.z - p2.x) * (p2.w - p2.y);
        float ap3 = (p3.z - p3.x) * (p3.w - p3.y);
        int base0 = 0, base1 = 0, base2 = 0, base3 = 0;
        #pragma unroll
        for (int pass = 0; pass < NT / 64; ++pass) {
            int j = (pass << 6) + lane;
            float4 t = t_lds[j];                   // shared by all 4 rows
            float at = (t.z - t.x) * (t.w - t.y);  // shared
            float w0 = fmaxf(fminf(p0.z, t.z) - fmaxf(p0.x, t.x), 0.f);
            float h0 = fmaxf(fminf(p0.w, t.w) - fmaxf(p0.y, t.y), 0.f);
            float in0 = w0 * h0;
            float iou0 = in0 * __builtin_amdgcn_rcpf((ap0 + at) - in0);
            float w1 = fmaxf(fminf(p1.z, t.z) - fmaxf(p1.x, t.x), 0.f);
            float h1 = fmaxf(fminf(p1.w, t.w) - fmaxf(p1.y, t.y), 0.f);
            float in1 = w1 * h1;
            float iou1 = in1 * __builtin_amdgcn_rcpf((ap1 + at) - in1);
            float w2 = fmaxf(fminf(p2.z, t.z) - fmaxf(p2.x, t.x), 0.f);
            float h2 = fmaxf(fminf(p2.w, t.w) - fmaxf(p2.y, t.y), 0.f);
            float in2 = w2 * h2;
            float iou2 = in2 * __builtin_amdgcn_rcpf((ap2 + at) - in2);
            float w3 = fmaxf(fminf(p3.z, t.z) - fmaxf(p3.x, t.x), 0.f);
            float h3 = fmaxf(fminf(p3.w, t.w) - fmaxf(p3.y, t.y), 0.f);
            float in3 = w3 * h3;
            float iou3 = in3 * __builtin_amdgcn_rcpf((ap3 + at) - in3);
            bool q0 = iou0 > IOU_THR, q1 = iou1 > IOU_THR;
            bool q2 = iou2 > IOU_THR, q3 = iou3 > IOU_THR;
            unsigned long long m0 = __ballot(q0), m1 = __ballot(q1);
            unsigned long long m2 = __ballot(q2), m3 = __ballot(q3);
            if (q0) {
                int off = base0 + __popcll(m0 & lmask);
                if (off < CAP)
                    cands[(size_t)off * NROWS + row0 + rr]     = make_float2(iou0, __int_as_float(j));
            }
            if (q1) {
                int off = base1 + __popcll(m1 & lmask);
                if (off < CAP)
                    cands[(size_t)off * NROWS + row0 + rr + 1] = make_float2(iou1, __int_as_float(j));
            }
            if (q2) {
                int off = base2 + __popcll(m2 & lmask);
                if (off < CAP)
                    cands[(size_t)off * NROWS + row0 + rr + 2] = make_float2(iou2, __int_as_float(j));
            }
            if (q3) {
                int off = base3 + __popcll(m3 & lmask);
                if (off < CAP)
                    cands[(size_t)off * NROWS + row0 + rr + 3] = make_float2(iou3, __int_as_float(j));
            }
            base0 += __popcll(m0); base1 += __popcll(m1);
            base2 += __popcll(m2); base3 += __popcll(m3);
        }
        if (lane == 0) {
            counts[row0 + rr]     = base0;         // > CAP flags overflow
            counts[row0 + rr + 1] = base1;
            counts[row0 + rr + 2] = base2;
            counts[row0 + rr + 3] = base3;
        }
    }
}

// ---------------------------------------------------------------------------
// Kernel 2: windowed auction — R13-16 config (T_WIN=1024, 4 windows, R10
// protocol, measured ~30us) + R15 fused reduce. claim[j] = min proposer
// (monotone) -> unique fixed point == serial greedy. Cross-wave visibility
// via barriers only (R11 lesson); cross-block via threadfence + atomicAdd.
// ---------------------------------------------------------------------------
__global__ __launch_bounds__(T_WIN) void win_auction(
    const float4* __restrict__ pred, const float4* __restrict__ tgt,
    const int* __restrict__ counts, const float2* __restrict__ cands,
    float* __restrict__ per_img, int* __restrict__ done_ctr,
    float* __restrict__ out)
{
    __shared__ float4   t_lds[NT];       // 8 KB
    __shared__ unsigned claim[NT];       // 2 KB
    __shared__ int lastprop;             // monotone round stamp
    __shared__ unsigned char winovf[NWIN];
    __shared__ int ovf_min, ovf_res;
    __shared__ float rvv[T_WIN / 64];  __shared__ int rjj[T_WIN / 64];
    __shared__ float rls[T_WIN / 64];  __shared__ float rcs[T_WIN / 64];

    const int b = blockIdx.x, t = threadIdx.x, gbase = b * NM;
    const int wv = t >> 6, lane = t & 63;

    if (t < NT) {                        // T_WIN > NT: guard target-indexed init
        t_lds[t] = tgt[b * NT + t];
        claim[t] = SENT;
    }
    if (t < NWIN) winovf[t] = 0;
    if (t == 0) lastprop = -1;
    __syncthreads();

    // all counts up front (NWIN coalesced loads), flag overflow windows
    int allCnt[NWIN];
    #pragma unroll
    for (int k = 0; k < NWIN; ++k) {
        allCnt[k] = counts[gbase + k * T_WIN + t];
        if (allCnt[k] > CAP) winovf[k] = 1;
    }
    // prefetch window 0 candidates into registers
    float2 nC[CAP];
    #pragma unroll
    for (int e = 0; e < CAP; ++e) nC[e] = cands[(size_t)e * NROWS + gbase + t];
    __syncthreads();                      // winovf visible to all

    int rglob = 0;
    float2 cC[CAP];
    for (int w = 0; w < NWIN; ++w) {
        #pragma unroll
        for (int e = 0; e < CAP; ++e) cC[e] = nC[e];
        const int cCnt = allCnt[w];
        if (w + 1 < NWIN) {               // prefetch next window; hides under rounds
            #pragma unroll
            for (int e = 0; e < CAP; ++e)
                nC[e] = cands[(size_t)e * NROWS + gbase + (w + 1) * T_WIN + t];
        }
        const unsigned row = (unsigned)(w * T_WIN + t);
        int  stt  = (cCnt > 0 && cCnt <= CAP) ? 0 : 2;   // 0=UNRES 1=HOLD 2=DONE
        int  myj  = -1;
        bool isovf = (cCnt > CAP);
        int  ovfj  = -1;

        for (;;) {
            // ---- auction rounds to window fixed point (1 barrier/round) ----
            for (;;) {
                if (stt == 1 && claim[myj] != row) stt = 0;      // sniped: rejoin
                bool did = false;
                if (stt == 0) {
                    for (int it = 0; it <= CAP; ++it) {          // bounded retry
                        float bv = -1.f; int bj = -1;
                        #pragma unroll
                        for (int e = 0; e < CAP; ++e) {          // independent reads
                            float2 ce = cC[e];
                            int j = __float_as_int(ce.y) & (NT - 1);
                            unsigned cj = claim[j];
                            if (e < cCnt && cj >= row && ce.x > bv) { bv = ce.x; bj = j; }
                        }
                        if (bj < 0) { stt = 2; break; }          // invalid (permanent)
                        did = true;
                        unsigned old = atomicMin(&claim[bj], row);
                        if (old >= row) { myj = bj; stt = 1; break; }   // settled
                        // lost: claim[bj] < row is permanent -> excluded next scan
                    }
                }
                if (did) lastprop = rglob;    // benign: all writers store same value
                __syncthreads();
                int lp = lastprop;
                ++rglob;
                if (lp < rglob - 1) break;    // zero-proposal round: fixed point
            }
            // ---- overflow fallback (count > CAP, ~never) ----
            if (!winovf[w]) break;
            if (t == 0) ovf_min = 0x7FFFFFFF;
            __syncthreads();
            bool pend = isovf && (ovfj < 0 || claim[ovfj] != row);
            if (pend) atomicMin(&ovf_min, (int)row);
            __syncthreads();
            const int rowF = ovf_min;                            // uniform
            if (rowF == 0x7FFFFFFF) break;                       // window done
            {   // exact claim-aware argmax over all 512 targets (thread t = target t)
                float4 p4 = pred[gbase + rowF];                  // uniform address
                float v = -1.f; int bj = NT;
                if (t < NT) {
                    float4 tt = t_lds[t];
                    float area_p = (p4.z - p4.x) * (p4.w - p4.y);
                    float area_t = (tt.z - tt.x) * (tt.w - tt.y);
                    float wd = fmaxf(fminf(p4.z, tt.z) - fmaxf(p4.x, tt.x), 0.f);
                    float hd = fmaxf(fminf(p4.w, tt.w) - fmaxf(p4.y, tt.y), 0.f);
                    float inter = wd * hd;
                    float iou = inter / ((area_p + area_t) - inter);
                    bool freej = claim[t] > (unsigned)rowF;      // smaller = final-used
                    v = freej ? iou : -1.f;
                    bj = freej ? t : NT;
                }
                #pragma unroll
                for (int off = 1; off < 64; off <<= 1) {
                    float ov = __shfl_xor(v, off);
                    int   oj = __shfl_xor(bj, off);
                    if (ov > v || (ov == v && oj < bj)) { v = ov; bj = oj; }
                }
                if (lane == 0) { rvv[wv] = v; rjj[wv] = bj; }
            }
            __syncthreads();
            if (t == 0) {
                float v = rvv[0]; int bj = rjj[0];
                for (int q = 1; q < T_WIN / 64; ++q)
                    if (rvv[q] > v || (rvv[q] == v && rjj[q] < bj)) { v = rvv[q]; bj = rjj[q]; }
                if (v > IOU_THR) { ovf_res = bj; claim[bj] = (unsigned)rowF; }  // steal
                else ovf_res = -1;
            }
            __syncthreads();
            if ((int)row == rowF) {
                if (ovf_res >= 0) ovfj = ovf_res;   // matched (recorded in claim)
                else isovf = false;                 // permanently invalid
            }
            // displaced holder (if any) re-detected at next round's recheck
        }
    }
    __syncthreads();

    // ---- commit by target: claim[j]==r <=> r matched j (unique fixed point) ----
    float ls = 0.f, cs = 0.f;
    if (t < NT) {
        unsigned r = claim[t];
        if (r != SENT) {
            float4 p4 = pred[gbase + (int)r];
            float4 tt = t_lds[t];
            float inter = fmaxf(fminf(p4.z, tt.z) - fmaxf(p4.x, tt.x), 0.f) *
                          fmaxf(fminf(p4.w, tt.w) - fmaxf(p4.y, tt.y), 0.f);
            float area_p = (p4.z - p4.x) * (p4.w - p4.y);
            float area_t = (tt.z - tt.x) * (tt.w - tt.y);
            float uni = area_p + area_t - inter;
            float iou = inter / (uni + EPSG);
            float enc = (fmaxf(p4.z, tt.z) - fminf(p4.x, tt.x)) *
                        (fmaxf(p4.w, tt.w) - fminf(p4.y, tt.y));
            float giou = iou - (enc - uni) / (enc + EPSG);
            ls = 1.f - giou;
            cs = 1.f;
        }
    }
    #pragma unroll
    for (int off = 32; off >= 1; off >>= 1) {
        ls += __shfl_xor(ls, off);
        cs += __shfl_xor(cs, off);
    }
    if (lane == 0) { rls[wv] = ls; rcs[wv] = cs; }
    __syncthreads();
    if (t == 0) {
        float L = 0.f, C = 0.f;
        for (int q = 0; q < T_WIN / 64; ++q) { L += rls[q]; C += rcs[q]; }
        per_img[b] = (C > 0.f) ? L / C : 0.f;
        __threadfence();                                  // publish per_img[b]
        int ret = atomicAdd(done_ctr, 1);                 // device-scope
        if (ret == NB - 1) {                              // last block reduces
            __threadfence();                              // acquire all per_img
            volatile float* vp = per_img;
            float s = 0.f;
            for (int i = 0; i < NB; ++i) s += vp[i];      // fixed order
            out[0] = s / (float)NB;
        }
    }
}

extern "C" void kernel_launch(void* const* d_in, const int* in_sizes, int n_in,
                              void* d_out, int out_size, void* d_ws, size_t ws_size,
                              hipStream_t stream)
{
    const float4* pred = (const float4*)d_in[0];   // [16,4096,4] f32
    const float4* tgt  = (const float4*)d_in[1];   // [16,512,4]  f32

    char* ws = (char*)d_ws;
    // layout: counts [NROWS] i32 | cands [CAP*NROWS] float2 | per_img [NB] f32 | ctr
    int*    counts  = (int*)ws;
    size_t  off1    = (size_t)NROWS * sizeof(int);                 // 256 KB
    float2* cands   = (float2*)(ws + off1);
    size_t  off2    = off1 + (size_t)CAP * NROWS * sizeof(float2); // +8 MB
    float*  per_img = (float*)(ws + off2);
    int*    done_ctr = (int*)(ws + off2 + 64);

    cand_kernel<<<NROWS / 32, 256, 0, stream>>>(pred, tgt, counts, cands, done_ctr);
    win_auction<<<NB, T_WIN, 0, stream>>>(pred, tgt, counts, cands, per_img,
                                          done_ctr, (float*)d_out);
}

// Round 20
// 54.183 us; speedup vs baseline: 1.4415x; 1.0394x over previous
//
#include <hip/hip_runtime.h>
#include <math.h>

#define NB   16      // batch
#define NM   4096    // preds per image
#define NT   512     // targets per image
#define CAP  16      // max candidates per row (overflow -> exact fallback)
#define IOU_THR 0.1f
#define EPSG 1e-7f
#define NROWS (NB*NM)
#define T_WIN 1024           // threads per auction block
#define WROWS 2048           // rows per window (R20: was 1024)
#define NWIN  (NM / WROWS)   // 2 ascending windows, 2 rows/thread/window
#define SENT  0xFFFFFFFFu

// ---------------------------------------------------------------------------
// Kernel 1: wave-per-row candidate build, v4 (R19, measured-good): 4 rows per
// pass + fast-rcp IoU (value only drives threshold and within-row ordering —
// exact GIoU recomputed at commit) + 32 rows/block (2048 blocks). Ballot
// compaction, ascending-j order, e-major storage. Zeroes fused-reduce ctr.
// ---------------------------------------------------------------------------
__global__ __launch_bounds__(256) void cand_kernel(
    const float4* __restrict__ pred, const float4* __restrict__ tgt,
    int* __restrict__ counts, float2* __restrict__ cands, int* __restrict__ done_ctr)
{
    __shared__ float4 t_lds[NT];
    const int rb = blockIdx.x * 32;          // 32 rows per block, same image
    const int b  = rb >> 12;                 // NM = 4096
    if (blockIdx.x == 0 && threadIdx.x == 0) *done_ctr = 0;
    #pragma unroll
    for (int i = 0; i < 2; ++i)
        t_lds[i * 256 + threadIdx.x] = tgt[b * NT + i * 256 + threadIdx.x];
    __syncthreads();

    const int wv = threadIdx.x >> 6, lane = threadIdx.x & 63;
    const int row0 = rb + wv * 8;            // 8 rows per wave (2 quads)
    const unsigned long long lmask = (1ull << lane) - 1ull;

    float4 pn0 = pred[row0],     pn1 = pred[row0 + 1];
    float4 pn2 = pred[row0 + 2], pn3 = pred[row0 + 3];
    for (int rr = 0; rr < 8; rr += 4) {
        float4 p0 = pn0, p1 = pn1, p2 = pn2, p3 = pn3;
        if (rr + 4 < 8) {                    // prefetch next quad early
            pn0 = pred[row0 + rr + 4]; pn1 = pred[row0 + rr + 5];
            pn2 = pred[row0 + rr + 6]; pn3 = pred[row0 + rr + 7];
        }
        float ap0 = (p0.z - p0.x) * (p0.w - p0.y);
        float ap1 = (p1.z - p1.x) * (p1.w - p1.y);
        float ap2 = (p2.z - p2.x) * (p2.w - p2.y);
        float ap3 = (p3.z - p3.x) * (p3.w - p3.y);
        int base0 = 0, base1 = 0, base2 = 0, base3 = 0;
        #pragma unroll
        for (int pass = 0; pass < NT / 64; ++pass) {
            int j = (pass << 6) + lane;
            float4 t = t_lds[j];                   // shared by all 4 rows
            float at = (t.z - t.x) * (t.w - t.y);  // shared
            float w0 = fmaxf(fminf(p0.z, t.z) - fmaxf(p0.x, t.x), 0.f);
            float h0 = fmaxf(fminf(p0.w, t.w) - fmaxf(p0.y, t.y), 0.f);
            float in0 = w0 * h0;
            float iou0 = in0 * __builtin_amdgcn_rcpf((ap0 + at) - in0);
            float w1 = fmaxf(fminf(p1.z, t.z) - fmaxf(p1.x, t.x), 0.f);
            float h1 = fmaxf(fminf(p1.w, t.w) - fmaxf(p1.y, t.y), 0.f);
            float in1 = w1 * h1;
            float iou1 = in1 * __builtin_amdgcn_rcpf((ap1 + at) - in1);
            float w2 = fmaxf(fminf(p2.z, t.z) - fmaxf(p2.x, t.x), 0.f);
            float h2 = fmaxf(fminf(p2.w, t.w) - fmaxf(p2.y, t.y), 0.f);
            float in2 = w2 * h2;
            float iou2 = in2 * __builtin_amdgcn_rcpf((ap2 + at) - in2);
            float w3 = fmaxf(fminf(p3.z, t.z) - fmaxf(p3.x, t.x), 0.f);
            float h3 = fmaxf(fminf(p3.w, t.w) - fmaxf(p3.y, t.y), 0.f);
            float in3 = w3 * h3;
            float iou3 = in3 * __builtin_amdgcn_rcpf((ap3 + at) - in3);
            bool q0 = iou0 > IOU_THR, q1 = iou1 > IOU_THR;
            bool q2 = iou2 > IOU_THR, q3 = iou3 > IOU_THR;
            unsigned long long m0 = __ballot(q0), m1 = __ballot(q1);
            unsigned long long m2 = __ballot(q2), m3 = __ballot(q3);
            if (q0) {
                int off = base0 + __popcll(m0 & lmask);
                if (off < CAP)
                    cands[(size_t)off * NROWS + row0 + rr]     = make_float2(iou0, __int_as_float(j));
            }
            if (q1) {
                int off = base1 + __popcll(m1 & lmask);
                if (off < CAP)
                    cands[(size_t)off * NROWS + row0 + rr + 1] = make_float2(iou1, __int_as_float(j));
            }
            if (q2) {
                int off = base2 + __popcll(m2 & lmask);
                if (off < CAP)
                    cands[(size_t)off * NROWS + row0 + rr + 2] = make_float2(iou2, __int_as_float(j));
            }
            if (q3) {
                int off = base3 + __popcll(m3 & lmask);
                if (off < CAP)
                    cands[(size_t)off * NROWS + row0 + rr + 3] = make_float2(iou3, __int_as_float(j));
            }
            base0 += __popcll(m0); base1 += __popcll(m1);
            base2 += __popcll(m2); base3 += __popcll(m3);
        }
        if (lane == 0) {
            counts[row0 + rr]     = base0;         // > CAP flags overflow
            counts[row0 + rr + 1] = base1;
            counts[row0 + rr + 2] = base2;
            counts[row0 + rr + 3] = base3;
        }
    }
}

// ---------------------------------------------------------------------------
// Kernel 2: windowed auction — R10 protocol, 2 windows of 2048 rows, 2 rows
// per thread per window (thread t owns rows w*2048+t and w*2048+1024+t; all
// static register indexing). Ascending windows to internal fixed point are
// FINAL (claim influence flows strictly upward). Fused final reduce.
// claim[j] = min proposer (monotone) -> unique fixed point == serial greedy.
// Cross-wave visibility via barriers only (R11 lesson).
// ---------------------------------------------------------------------------
__global__ __launch_bounds__(T_WIN) void win_auction(
    const float4* __restrict__ pred, const float4* __restrict__ tgt,
    const int* __restrict__ counts, const float2* __restrict__ cands,
    float* __restrict__ per_img, int* __restrict__ done_ctr,
    float* __restrict__ out)
{
    __shared__ float4   t_lds[NT];       // 8 KB
    __shared__ unsigned claim[NT];       // 2 KB
    __shared__ int lastprop;             // monotone round stamp
    __shared__ unsigned char winovf[NWIN];
    __shared__ int ovf_min, ovf_res;
    __shared__ float rvv[T_WIN / 64];  __shared__ int rjj[T_WIN / 64];
    __shared__ float rls[T_WIN / 64];  __shared__ float rcs[T_WIN / 64];

    const int b = blockIdx.x, t = threadIdx.x, gbase = b * NM;
    const int wv = t >> 6, lane = t & 63;

    if (t < NT) {                        // T_WIN > NT: guard target-indexed init
        t_lds[t] = tgt[b * NT + t];
        claim[t] = SENT;
    }
    if (t < NWIN) winovf[t] = 0;
    if (t == 0) lastprop = -1;
    __syncthreads();

    // counts for both windows x both row-slots (coalesced), flag overflow
    int cw00, cw01, cw10, cw11;
    cw00 = counts[gbase + 0 * WROWS + t];
    cw01 = counts[gbase + 0 * WROWS + T_WIN + t];
    cw10 = counts[gbase + 1 * WROWS + t];
    cw11 = counts[gbase + 1 * WROWS + T_WIN + t];
    if (cw00 > CAP || cw01 > CAP) winovf[0] = 1;   // same-value byte stores: benign
    if (cw10 > CAP || cw11 > CAP) winovf[1] = 1;
    __syncthreads();                      // winovf visible to all

    int rglob = 0;
    #pragma unroll 1
    for (int w = 0; w < NWIN; ++w) {
        // load this window's candidates into named register arrays
        float2 c0[CAP], c1[CAP];
        #pragma unroll
        for (int e = 0; e < CAP; ++e) {
            c0[e] = cands[(size_t)e * NROWS + gbase + w * WROWS + t];
            c1[e] = cands[(size_t)e * NROWS + gbase + w * WROWS + T_WIN + t];
        }
        const unsigned row0 = (unsigned)(w * WROWS + t);
        const unsigned row1 = (unsigned)(w * WROWS + T_WIN + t);
        const int cnt0 = (w == 0) ? cw00 : cw10;
        const int cnt1 = (w == 0) ? cw01 : cw11;
        int  stt0 = (cnt0 > 0 && cnt0 <= CAP) ? 0 : 2;   // 0=UNRES 1=HOLD 2=DONE
        int  stt1 = (cnt1 > 0 && cnt1 <= CAP) ? 0 : 2;
        int  myj0 = -1, myj1 = -1;
        bool isovf0 = (cnt0 > CAP), isovf1 = (cnt1 > CAP);
        int  ovfj0 = -1, ovfj1 = -1;

        for (;;) {
            // ---- auction rounds to window fixed point (1 barrier/round) ----
            for (;;) {
                bool did = false;
                // row slot 0
                if (stt0 == 1 && claim[myj0] != row0) stt0 = 0;  // sniped: rejoin
                if (stt0 == 0) {
                    for (int it = 0; it <= CAP; ++it) {          // bounded retry
                        float bv = -1.f; int bj = -1;
                        #pragma unroll
                        for (int e = 0; e < CAP; ++e) {          // independent reads
                            float2 ce = c0[e];
                            int j = __float_as_int(ce.y) & (NT - 1);
                            unsigned cj = claim[j];
                            if (e < cnt0 && cj >= row0 && ce.x > bv) { bv = ce.x; bj = j; }
                        }
                        if (bj < 0) { stt0 = 2; break; }         // invalid (permanent)
                        did = true;
                        unsigned old = atomicMin(&claim[bj], row0);
                        if (old >= row0) { myj0 = bj; stt0 = 1; break; }  // settled
                    }
                }
                // row slot 1
                if (stt1 == 1 && claim[myj1] != row1) stt1 = 0;  // sniped: rejoin
                if (stt1 == 0) {
                    for (int it = 0; it <= CAP; ++it) {
                        float bv = -1.f; int bj = -1;
                        #pragma unroll
                        for (int e = 0; e < CAP; ++e) {
                            float2 ce = c1[e];
                            int j = __float_as_int(ce.y) & (NT - 1);
                            unsigned cj = claim[j];
                            if (e < cnt1 && cj >= row1 && ce.x > bv) { bv = ce.x; bj = j; }
                        }
                        if (bj < 0) { stt1 = 2; break; }
                        did = true;
                        unsigned old = atomicMin(&claim[bj], row1);
                        if (old >= row1) { myj1 = bj; stt1 = 1; break; }
                    }
                }
                if (did) lastprop = rglob;    // benign: all writers store same value
                __syncthreads();
                int lp = lastprop;
                ++rglob;
                if (lp < rglob - 1) break;    // zero-proposal round: fixed point
            }
            // ---- overflow fallback (count > CAP, ~never) ----
            if (!winovf[w]) break;
            if (t == 0) ovf_min = 0x7FFFFFFF;
            __syncthreads();
            bool pend0 = isovf0 && (ovfj0 < 0 || claim[ovfj0] != row0);
            bool pend1 = isovf1 && (ovfj1 < 0 || claim[ovfj1] != row1);
            if (pend0) atomicMin(&ovf_min, (int)row0);
            if (pend1) atomicMin(&ovf_min, (int)row1);
            __syncthreads();
            const int rowF = ovf_min;                            // uniform
            if (rowF == 0x7FFFFFFF) break;                       // window done
            {   // exact claim-aware argmax over all 512 targets (thread t = target t)
                float4 p4 = pred[gbase + rowF];                  // uniform address
                float v = -1.f; int bj = NT;
                if (t < NT) {
                    float4 tt = t_lds[t];
                    float area_p = (p4.z - p4.x) * (p4.w - p4.y);
                    float area_t = (tt.z - tt.x) * (tt.w - tt.y);
                    float wd = fmaxf(fminf(p4.z, tt.z) - fmaxf(p4.x, tt.x), 0.f);
                    float hd = fmaxf(fminf(p4.w, tt.w) - fmaxf(p4.y, tt.y), 0.f);
                    float inter = wd * hd;
                    float iou = inter / ((area_p + area_t) - inter);
                    bool freej = claim[t] > (unsigned)rowF;      // smaller = final-used
                    v = freej ? iou : -1.f;
                    bj = freej ? t : NT;
                }
                #pragma unroll
                for (int off = 1; off < 64; off <<= 1) {
                    float ov = __shfl_xor(v, off);
                    int   oj = __shfl_xor(bj, off);
                    if (ov > v || (ov == v && oj < bj)) { v = ov; bj = oj; }
                }
                if (lane == 0) { rvv[wv] = v; rjj[wv] = bj; }
            }
            __syncthreads();
            if (t == 0) {
                float v = rvv[0]; int bj = rjj[0];
                for (int q = 1; q < T_WIN / 64; ++q)
                    if (rvv[q] > v || (rvv[q] == v && rjj[q] < bj)) { v = rvv[q]; bj = rjj[q]; }
                if (v > IOU_THR) { ovf_res = bj; claim[bj] = (unsigned)rowF; }  // steal
                else ovf_res = -1;
            }
            __syncthreads();
            if ((int)row0 == rowF) {
                if (ovf_res >= 0) ovfj0 = ovf_res;  // matched (recorded in claim)
                else isovf0 = false;                // permanently invalid
            }
            if ((int)row1 == rowF) {
                if (ovf_res >= 0) ovfj1 = ovf_res;
                else isovf1 = false;
            }
            // displaced holder (if any) re-detected at next round's recheck
        }
    }
    __syncthreads();

    // ---- commit by target: claim[j]==r <=> r matched j (unique fixed point) ----
    float ls = 0.f, cs = 0.f;
    if (t < NT) {
        unsigned r = claim[t];
        if (r != SENT) {
            float4 p4 = pred[gbase + (int)r];
            float4 tt = t_lds[t];
            float inter = fmaxf(fminf(p4.z, tt.z) - fmaxf(p4.x, tt.x), 0.f) *
                          fmaxf(fminf(p4.w, tt.w) - fmaxf(p4.y, tt.y), 0.f);
            float area_p = (p4.z - p4.x) * (p4.w - p4.y);
            float area_t = (tt.z - tt.x) * (tt.w - tt.y);
            float uni = area_p + area_t - inter;
            float iou = inter / (uni + EPSG);
            float enc = (fmaxf(p4.z, tt.z) - fminf(p4.x, tt.x)) *
                        (fmaxf(p4.w, tt.w) - fminf(p4.y, tt.y));
            float giou = iou - (enc - uni) / (enc + EPSG);
            ls = 1.f - giou;
            cs = 1.f;
        }
    }
    #pragma unroll
    for (int off = 32; off >= 1; off >>= 1) {
        ls += __shfl_xor(ls, off);
        cs += __shfl_xor(cs, off);
    }
    if (lane == 0) { rls[wv] = ls; rcs[wv] = cs; }
    __syncthreads();
    if (t == 0) {
        float L = 0.f, C = 0.f;
        for (int q = 0; q < T_WIN / 64; ++q) { L += rls[q]; C += rcs[q]; }
        per_img[b] = (C > 0.f) ? L / C : 0.f;
        __threadfence();                                  // publish per_img[b]
        int ret = atomicAdd(done_ctr, 1);                 // device-scope
        if (ret == NB - 1) {                              // last block reduces
            __threadfence();                              // acquire all per_img
            volatile float* vp = per_img;
            float s = 0.f;
            for (int i = 0; i < NB; ++i) s += vp[i];      // fixed order
            out[0] = s / (float)NB;
        }
    }
}

extern "C" void kernel_launch(void* const* d_in, const int* in_sizes, int n_in,
                              void* d_out, int out_size, void* d_ws, size_t ws_size,
                              hipStream_t stream)
{
    const float4* pred = (const float4*)d_in[0];   // [16,4096,4] f32
    const float4* tgt  = (const float4*)d_in[1];   // [16,512,4]  f32

    char* ws = (char*)d_ws;
    // layout: counts [NROWS] i32 | cands [CAP*NROWS] float2 | per_img [NB] f32 | ctr
    int*    counts  = (int*)ws;
    size_t  off1    = (size_t)NROWS * sizeof(int);                 // 256 KB
    float2* cands   = (float2*)(ws + off1);
    size_t  off2    = off1 + (size_t)CAP * NROWS * sizeof(float2); // +8 MB
    float*  per_img = (float*)(ws + off2);
    int*    done_ctr = (int*)(ws + off2 + 64);

    cand_kernel<<<NROWS / 32, 256, 0, stream>>>(pred, tgt, counts, cands, done_ctr);
    win_auction<<<NB, T_WIN, 0, stream>>>(pred, tgt, counts, cands, per_img,
                                          done_ctr, (float*)d_out);
}